// Round 2
// baseline (1297.815 us; speedup 1.0000x reference)
//
#include <hip/hip_runtime.h>
#include <hip/hip_bf16.h>

#define N_NODES 100000

// ---------------------------------------------------------------------------
// Graph prep: histogram -> dis -> scan -> scatter (counting sort to CSR)
// ---------------------------------------------------------------------------

__global__ __launch_bounds__(256) void k_zero_int(int* __restrict__ p, int n) {
    int i = blockIdx.x * 256 + threadIdx.x;
    if (i < n) p[i] = 0;
}

// histogram of dst
__global__ __launch_bounds__(256) void k_count(const int* __restrict__ ei, int E,
                                               int* __restrict__ cnt) {
    for (int e = blockIdx.x * 256 + threadIdx.x; e < E; e += gridDim.x * 256)
        atomicAdd(&cnt[ei[E + e]], 1);
}

// deg_inv_sqrt: deg = in-degree + 1 (self loop), always > 0
__global__ __launch_bounds__(256) void k_dis(const int* __restrict__ cnt,
                                             float* __restrict__ dis, int n) {
    int i = blockIdx.x * 256 + threadIdx.x;
    if (i < n) dis[i] = 1.0f / sqrtf((float)(cnt[i] + 1));
}

// single-block chunked exclusive scan (wave-shuffle based), n = 100k -> 98 chunks
__global__ __launch_bounds__(1024) void k_scan(const int* __restrict__ cnt,
                                               int* __restrict__ row_ptr, int n) {
    __shared__ int wsum[16];
    const int tid = threadIdx.x;
    const int lane = tid & 63;
    const int wv = tid >> 6;
    int offset = 0;
    for (int base = 0; base < n; base += 1024) {
        int i = base + tid;
        int v = (i < n) ? cnt[i] : 0;
        int x = v;
        #pragma unroll
        for (int d = 1; d < 64; d <<= 1) {
            int t = __shfl_up(x, d, 64);
            if (lane >= d) x += t;
        }
        if (lane == 63) wsum[wv] = x;
        __syncthreads();
        int woff = 0, total = 0;
        #pragma unroll
        for (int w = 0; w < 16; ++w) {
            int s = wsum[w];
            if (w < wv) woff += s;
            total += s;
        }
        if (i < n) row_ptr[i] = offset + woff + x - v;  // exclusive
        offset += total;
        __syncthreads();
    }
    if (tid == 0) row_ptr[n] = offset;
}

__global__ __launch_bounds__(256) void k_copy_int(const int* __restrict__ s,
                                                  int* __restrict__ d, int n) {
    int i = blockIdx.x * 256 + threadIdx.x;
    if (i < n) d[i] = s[i];
}

// counting-sort scatter: edge e -> slot in dst's CSR row; also precompute norm
__global__ __launch_bounds__(256) void k_scatter(const int* __restrict__ ei, int E,
                                                 const float* __restrict__ dis,
                                                 int* __restrict__ cursor,
                                                 int* __restrict__ ssrc,
                                                 float* __restrict__ snorm) {
    for (int e = blockIdx.x * 256 + threadIdx.x; e < E; e += gridDim.x * 256) {
        int s = ei[e];
        int d = ei[E + e];
        int pos = atomicAdd(&cursor[d], 1);
        ssrc[pos] = s;
        snorm[pos] = dis[s] * dis[d];
    }
}

// ---------------------------------------------------------------------------
// fp32 GEMM: C[M,N] = A[M,K] @ B[K,N].  128x64 tile, 256 thr, 8x4 per thread.
// All global loads are float4. LDS: As[k][m] (transposed), Bs[k][n].
// ---------------------------------------------------------------------------
__global__ __launch_bounds__(256) void k_gemm(const float* __restrict__ A,
                                              const float* __restrict__ B,
                                              float* __restrict__ C,
                                              int M, int N, int K) {
    __shared__ float As[16][132];  // [k][m], pad 128+4
    __shared__ float Bs[16][68];   // [k][n], pad 64+4
    const int tid = threadIdx.x;
    const int tx = tid & 15;       // n-dim thread coord (4 cols each)
    const int ty = tid >> 4;       // m-dim thread coord (8 rows each)
    const int row0 = blockIdx.y * 128;
    const int col0 = blockIdx.x * 64;

    // global-load coords
    const int am = tid >> 2;        // 0..63 (row within half-tile)
    const int ak = (tid & 3) * 4;   // k chunk 0/4/8/12
    const int bk = tid >> 4;        // 0..15
    const int bn = (tid & 15) * 4;  // col chunk

    float acc[8][4] = {};

    for (int k0 = 0; k0 < K; k0 += 16) {
        // A tile 128x16 -> As[k][m], two 64-row passes, float4 per thread
        #pragma unroll
        for (int h = 0; h < 2; ++h) {
            const int m = am + h * 64;
            const int gr = row0 + m;
            float4 v = make_float4(0.f, 0.f, 0.f, 0.f);
            if (gr < M) v = *reinterpret_cast<const float4*>(&A[(size_t)gr * K + k0 + ak]);
            As[ak + 0][m] = v.x;
            As[ak + 1][m] = v.y;
            As[ak + 2][m] = v.z;
            As[ak + 3][m] = v.w;
        }
        // B tile 16x64 -> Bs[k][n], one float4 per thread (coalesced)
        {
            float4 v = *reinterpret_cast<const float4*>(&B[(size_t)(k0 + bk) * N + col0 + bn]);
            *reinterpret_cast<float4*>(&Bs[bk][bn]) = v;
        }
        __syncthreads();
        #pragma unroll
        for (int k = 0; k < 16; ++k) {
            float a[8], b[4];
            *reinterpret_cast<float4*>(&b[0]) = *reinterpret_cast<const float4*>(&Bs[k][tx * 4]);
            *reinterpret_cast<float4*>(&a[0]) = *reinterpret_cast<const float4*>(&As[k][ty * 8]);
            *reinterpret_cast<float4*>(&a[4]) = *reinterpret_cast<const float4*>(&As[k][ty * 8 + 4]);
            #pragma unroll
            for (int i = 0; i < 8; ++i)
                #pragma unroll
                for (int j = 0; j < 4; ++j)
                    acc[i][j] += a[i] * b[j];
        }
        __syncthreads();
    }
    #pragma unroll
    for (int i = 0; i < 8; ++i) {
        const int gr = row0 + ty * 8 + i;
        if (gr < M) {
            float4 v = make_float4(acc[i][0], acc[i][1], acc[i][2], acc[i][3]);
            *reinterpret_cast<float4*>(&C[(size_t)gr * N + col0 + tx * 4]) = v;
        }
    }
}

// ---------------------------------------------------------------------------
// Aggregation: one wave per node. out[d] = sum_in h[src]*norm + h[d]*dis^2 + b
// (optionally ReLU). D=256 -> float4/lane, D=128 -> float2/lane.
// Edge loop software-pipelined x2 with dual accumulators.
// ---------------------------------------------------------------------------
template <int D, bool RELU>
__global__ __launch_bounds__(256) void k_agg(const float* __restrict__ h,
                                             const int* __restrict__ row_ptr,
                                             const int* __restrict__ ssrc,
                                             const float* __restrict__ snorm,
                                             const float* __restrict__ dis,
                                             const float* __restrict__ bias,
                                             float* __restrict__ out) {
    constexpr int V = D / 64;
    const int wave = threadIdx.x >> 6;
    const int lane = threadIdx.x & 63;
    const int node = blockIdx.x * 4 + wave;
    if (node >= N_NODES) return;

    const int beg = row_ptr[node];
    const int end = row_ptr[node + 1];
    const int base = lane * V;

    float acc0[V], acc1[V];
    #pragma unroll
    for (int j = 0; j < V; ++j) { acc0[j] = 0.f; acc1[j] = 0.f; }

    int e = beg;
    for (; e + 2 <= end; e += 2) {
        const int s0 = ssrc[e];
        const int s1 = ssrc[e + 1];
        const float w0 = snorm[e];
        const float w1 = snorm[e + 1];
        const float* hp0 = h + (size_t)s0 * D + base;
        const float* hp1 = h + (size_t)s1 * D + base;
        if constexpr (V == 4) {
            float4 v0 = *reinterpret_cast<const float4*>(hp0);
            float4 v1 = *reinterpret_cast<const float4*>(hp1);
            acc0[0] += v0.x * w0; acc0[1] += v0.y * w0;
            acc0[2] += v0.z * w0; acc0[3] += v0.w * w0;
            acc1[0] += v1.x * w1; acc1[1] += v1.y * w1;
            acc1[2] += v1.z * w1; acc1[3] += v1.w * w1;
        } else {
            float2 v0 = *reinterpret_cast<const float2*>(hp0);
            float2 v1 = *reinterpret_cast<const float2*>(hp1);
            acc0[0] += v0.x * w0; acc0[1] += v0.y * w0;
            acc1[0] += v1.x * w1; acc1[1] += v1.y * w1;
        }
    }
    if (e < end) {
        const int s0 = ssrc[e];
        const float w0 = snorm[e];
        const float* hp0 = h + (size_t)s0 * D + base;
        if constexpr (V == 4) {
            float4 v0 = *reinterpret_cast<const float4*>(hp0);
            acc0[0] += v0.x * w0; acc0[1] += v0.y * w0;
            acc0[2] += v0.z * w0; acc0[3] += v0.w * w0;
        } else {
            float2 v0 = *reinterpret_cast<const float2*>(hp0);
            acc0[0] += v0.x * w0; acc0[1] += v0.y * w0;
        }
    }

    // self loop: norm = dis[node]^2
    {
        const float di = dis[node];
        const float w = di * di;
        const float* hp = h + (size_t)node * D + base;
        if constexpr (V == 4) {
            float4 v = *reinterpret_cast<const float4*>(hp);
            acc1[0] += v.x * w; acc1[1] += v.y * w;
            acc1[2] += v.z * w; acc1[3] += v.w * w;
        } else {
            float2 v = *reinterpret_cast<const float2*>(hp);
            acc1[0] += v.x * w; acc1[1] += v.y * w;
        }
    }

    // combine + bias (+ReLU)
    float r[V];
    #pragma unroll
    for (int j = 0; j < V; ++j) {
        float v = acc0[j] + acc1[j] + bias[base + j];
        if (RELU) v = fmaxf(v, 0.f);
        r[j] = v;
    }

    float* op = out + (size_t)node * D + base;
    if constexpr (V == 4) {
        *reinterpret_cast<float4*>(op) = make_float4(r[0], r[1], r[2], r[3]);
    } else {
        *reinterpret_cast<float2*>(op) = make_float2(r[0], r[1]);
    }
}

// ---------------------------------------------------------------------------

extern "C" void kernel_launch(void* const* d_in, const int* in_sizes, int n_in,
                              void* d_out, int out_size, void* d_ws, size_t ws_size,
                              hipStream_t stream) {
    const float* x  = (const float*)d_in[0];
    const int*   ei = (const int*)d_in[1];
    const float* W1 = (const float*)d_in[2];
    const float* b1 = (const float*)d_in[3];
    const float* W2 = (const float*)d_in[4];
    const float* b2 = (const float*)d_in[5];
    const float* W3 = (const float*)d_in[6];
    const float* b3 = (const float*)d_in[7];
    float* out = (float*)d_out;

    const int N = N_NODES;
    const int E = in_sizes[1] / 2;

    // workspace carve-up (256B aligned)
    char* ws = (char*)d_ws;
    size_t o = 0;
    auto take = [&](size_t bytes) {
        void* p = ws + o;
        o += (bytes + 255) & ~(size_t)255;
        return p;
    };
    float* dis     = (float*)take((size_t)N * 4);
    int*   row_ptr = (int*)  take((size_t)(N + 1) * 4);
    int*   cnt_cur = (int*)  take((size_t)N * 4);        // histogram, then cursor
    int*   ssrc    = (int*)  take((size_t)E * 4);
    float* snorm   = (float*)take((size_t)E * 4);
    float* bufA    = (float*)take((size_t)N * 256 * 4);
    float* bufB    = (float*)take((size_t)N * 256 * 4);
    (void)ws_size; (void)n_in; (void)out_size;

    const int nb_nodes = (N + 255) / 256;
    const int nb_edges = (E + 255) / 256;

    // ---- graph prep ----
    k_zero_int<<<nb_nodes, 256, 0, stream>>>(cnt_cur, N);
    k_count<<<nb_edges, 256, 0, stream>>>(ei, E, cnt_cur);
    k_dis<<<nb_nodes, 256, 0, stream>>>(cnt_cur, dis, N);
    k_scan<<<1, 1024, 0, stream>>>(cnt_cur, row_ptr, N);
    k_copy_int<<<nb_nodes, 256, 0, stream>>>(row_ptr, cnt_cur, N);
    k_scatter<<<nb_edges, 256, 0, stream>>>(ei, E, dis, cnt_cur, ssrc, snorm);

    const int agg_blocks = (N + 3) / 4;
    const int m_blocks = (N + 127) / 128;

    // ---- layer 1: h = x @ W1 ; agg -> relu ----
    k_gemm<<<dim3(256 / 64, m_blocks), 256, 0, stream>>>(x, W1, bufA, N, 256, 128);
    k_agg<256, true><<<agg_blocks, 256, 0, stream>>>(bufA, row_ptr, ssrc, snorm, dis, b1, bufB);

    // ---- layer 2 ----
    k_gemm<<<dim3(256 / 64, m_blocks), 256, 0, stream>>>(bufB, W2, bufA, N, 256, 256);
    k_agg<256, true><<<agg_blocks, 256, 0, stream>>>(bufA, row_ptr, ssrc, snorm, dis, b2, bufB);

    // ---- layer 3 (no relu, to d_out) ----
    k_gemm<<<dim3(128 / 64, m_blocks), 256, 0, stream>>>(bufB, W3, bufA, N, 128, 256);
    k_agg<128, false><<<agg_blocks, 256, 0, stream>>>(bufA, row_ptr, ssrc, snorm, dis, b3, out);
}

// Round 3
// 1041.095 us; speedup vs baseline: 1.2466x; 1.2466x over previous
//
#include <hip/hip_runtime.h>
#include <hip/hip_bf16.h>

#define N_NODES 100000
#define M_PAD   100096   // 782 * 128 — GEMM A-buffers padded so staging never goes OOB

typedef __attribute__((ext_vector_type(8))) short s8v;   // 8 x bf16 (4 VGPR) MFMA operand
typedef __attribute__((ext_vector_type(4))) float f4v;   // MFMA accumulator
typedef unsigned short u16;
typedef unsigned int   u32;

__device__ __forceinline__ u16 f2bf(float v) {
    __hip_bfloat16 b = __float2bfloat16(v);
    return __builtin_bit_cast(u16, b);
}
__device__ __forceinline__ float bf2f(u16 u) {
    __hip_bfloat16 b = __builtin_bit_cast(__hip_bfloat16, u);
    return __bfloat162float(b);
}

// async global->LDS, 16B per lane; LDS dest is wave-uniform base + lane*16
__device__ __forceinline__ void gl_lds16(const void* g, void* l) {
    __builtin_amdgcn_global_load_lds(
        (const __attribute__((address_space(1))) void*)g,
        (__attribute__((address_space(3))) void*)l, 16, 0, 0);
}

// ---------------------------------------------------------------------------
// Graph prep: histogram -> dis -> scan -> scatter (counting sort to CSR)
// ---------------------------------------------------------------------------

__global__ __launch_bounds__(256) void k_zero_int(int* __restrict__ p, int n) {
    int i = blockIdx.x * 256 + threadIdx.x;
    if (i < n) p[i] = 0;
}

__global__ __launch_bounds__(256) void k_count(const int* __restrict__ ei, int E,
                                               int* __restrict__ cnt) {
    for (int e = blockIdx.x * 256 + threadIdx.x; e < E; e += gridDim.x * 256)
        atomicAdd(&cnt[ei[E + e]], 1);
}

__global__ __launch_bounds__(256) void k_dis(const int* __restrict__ cnt,
                                             float* __restrict__ dis, int n) {
    int i = blockIdx.x * 256 + threadIdx.x;
    if (i < n) dis[i] = 1.0f / sqrtf((float)(cnt[i] + 1));
}

__global__ __launch_bounds__(1024) void k_scan(const int* __restrict__ cnt,
                                               int* __restrict__ row_ptr, int n) {
    __shared__ int wsum[16];
    const int tid = threadIdx.x;
    const int lane = tid & 63;
    const int wv = tid >> 6;
    int offset = 0;
    for (int base = 0; base < n; base += 1024) {
        int i = base + tid;
        int v = (i < n) ? cnt[i] : 0;
        int x = v;
        #pragma unroll
        for (int d = 1; d < 64; d <<= 1) {
            int t = __shfl_up(x, d, 64);
            if (lane >= d) x += t;
        }
        if (lane == 63) wsum[wv] = x;
        __syncthreads();
        int woff = 0, total = 0;
        #pragma unroll
        for (int w = 0; w < 16; ++w) {
            int s = wsum[w];
            if (w < wv) woff += s;
            total += s;
        }
        if (i < n) row_ptr[i] = offset + woff + x - v;  // exclusive
        offset += total;
        __syncthreads();
    }
    if (tid == 0) row_ptr[n] = offset;
}

__global__ __launch_bounds__(256) void k_copy_int(const int* __restrict__ s,
                                                  int* __restrict__ d, int n) {
    int i = blockIdx.x * 256 + threadIdx.x;
    if (i < n) d[i] = s[i];
}

__global__ __launch_bounds__(256) void k_scatter(const int* __restrict__ ei, int E,
                                                 const float* __restrict__ dis,
                                                 int* __restrict__ cursor,
                                                 int* __restrict__ ssrc,
                                                 float* __restrict__ snorm) {
    for (int e = blockIdx.x * 256 + threadIdx.x; e < E; e += gridDim.x * 256) {
        int s = ei[e];
        int d = ei[E + e];
        int pos = atomicAdd(&cursor[d], 1);
        ssrc[pos] = s;
        snorm[pos] = dis[s] * dis[d];
    }
}

// ---------------------------------------------------------------------------
// Weight prep: W[K][N] fp32 -> transposed split Wt_hi/Wt_lo [N][K] bf16
// ---------------------------------------------------------------------------
__global__ __launch_bounds__(256) void k_prep_w(const float* __restrict__ W,
                                                u16* __restrict__ Wth,
                                                u16* __restrict__ Wtl,
                                                int K, int N) {
    const int n = blockIdx.x;
    for (int k = threadIdx.x; k < K; k += 256) {
        float v = W[(size_t)k * N + n];
        u16 hi = f2bf(v);
        Wth[(size_t)n * K + k] = hi;
        Wtl[(size_t)n * K + k] = f2bf(v - bf2f(hi));
    }
}

// ---------------------------------------------------------------------------
// Split-bf16 MFMA GEMM: C[M,N] = (Ah+Al) @ (Bh+Bl)^T_storage, 3-product scheme.
// A: [M][K] bf16 pair, Bt: [N][K] bf16 pair (pre-transposed weights).
// Tile 128x128xBK32; 4 waves of 64x64 (4x4 16x16 fragments each).
// Fragment maps (gfx950 mfma_f32_16x16x32_bf16):
//   A: m=lane&15, k=(lane>>4)*8+e ; B: n=lane&15, k=(lane>>4)*8+e
//   D: col=lane&15, row=(lane>>4)*4+r   [HW-verified m89]
// ---------------------------------------------------------------------------
template <bool BIAS, bool RELU, bool SPLIT_OUT>
__global__ __launch_bounds__(256) void k_gemm_split(
    const u16* __restrict__ Ah, const u16* __restrict__ Al,
    const u16* __restrict__ Bth, const u16* __restrict__ Btl,
    const float* __restrict__ bias,
    float* __restrict__ Cf, u16* __restrict__ Ch, u16* __restrict__ Cl,
    int M, int N, int K) {
    __shared__ u16 Ahs[128 * 32];
    __shared__ u16 Als[128 * 32];
    __shared__ u16 Bhs[128 * 32];
    __shared__ u16 Bls[128 * 32];

    const int tid  = threadIdx.x;
    const int wid  = tid >> 6;
    const int lane = tid & 63;
    const int wm = wid >> 1;
    const int wn = wid & 1;
    const int row0 = blockIdx.y * 128;
    const int n0   = blockIdx.x * 128;

    const int srow  = lane >> 2;        // staging: row within 16-row group
    const int sbyte = (lane & 3) * 16;  // staging: byte offset within 64B row
    const int fr = lane & 15;           // fragment row/col
    const int kg = (lane >> 4) * 8;     // fragment k offset (bf16 elements)

    f4v acc[4][4];
    #pragma unroll
    for (int t = 0; t < 4; ++t)
        #pragma unroll
        for (int u = 0; u < 4; ++u)
            acc[t][u] = (f4v){0.f, 0.f, 0.f, 0.f};

    for (int k0 = 0; k0 < K; k0 += 32) {
        // stage 128x32 bf16 tiles (hi/lo of A and Bt): 8 gl_lds per wave
        #pragma unroll
        for (int g = 0; g < 2; ++g) {
            const int rloc = wid * 32 + g * 16;
            const size_t ga = (size_t)(row0 + rloc + srow) * K + k0;
            gl_lds16((const char*)(Ah + ga) + sbyte, &Ahs[rloc * 32]);
            gl_lds16((const char*)(Al + ga) + sbyte, &Als[rloc * 32]);
            const size_t gb = (size_t)(n0 + rloc + srow) * K + k0;
            gl_lds16((const char*)(Bth + gb) + sbyte, &Bhs[rloc * 32]);
            gl_lds16((const char*)(Btl + gb) + sbyte, &Bls[rloc * 32]);
        }
        __syncthreads();   // drains vmcnt before barrier (compiler-emitted)

        s8v bh[4], bl[4];
        #pragma unroll
        for (int u = 0; u < 4; ++u) {
            const int rb = (wn * 64 + u * 16 + fr) * 32 + kg;
            bh[u] = *(const s8v*)&Bhs[rb];
            bl[u] = *(const s8v*)&Bls[rb];
        }
        #pragma unroll
        for (int t = 0; t < 4; ++t) {
            const int ra = (wm * 64 + t * 16 + fr) * 32 + kg;
            const s8v ah = *(const s8v*)&Ahs[ra];
            const s8v al = *(const s8v*)&Als[ra];
            #pragma unroll
            for (int u = 0; u < 4; ++u) {
                acc[t][u] = __builtin_amdgcn_mfma_f32_16x16x32_bf16(ah, bh[u], acc[t][u], 0, 0, 0);
                acc[t][u] = __builtin_amdgcn_mfma_f32_16x16x32_bf16(ah, bl[u], acc[t][u], 0, 0, 0);
                acc[t][u] = __builtin_amdgcn_mfma_f32_16x16x32_bf16(al, bh[u], acc[t][u], 0, 0, 0);
            }
        }
        __syncthreads();
    }

    const int orow = (lane >> 4) * 4;
    #pragma unroll
    for (int u = 0; u < 4; ++u) {
        const int col = n0 + wn * 64 + u * 16 + fr;
        float bv = 0.f;
        if constexpr (BIAS) bv = bias[col];
        #pragma unroll
        for (int t = 0; t < 4; ++t) {
            #pragma unroll
            for (int r = 0; r < 4; ++r) {
                const int grow = row0 + wm * 64 + t * 16 + orow + r;
                if (grow < M) {
                    float v = acc[t][u][r] + bv;
                    if constexpr (RELU) v = fmaxf(v, 0.f);
                    if constexpr (SPLIT_OUT) {
                        const u16 hi = f2bf(v);
                        Ch[(size_t)grow * N + col] = hi;
                        Cl[(size_t)grow * N + col] = f2bf(v - bf2f(hi));
                    } else {
                        Cf[(size_t)grow * N + col] = v;
                    }
                }
            }
        }
    }
}

// ---------------------------------------------------------------------------
// Aggregation: one wave per node. res = sum_in h[src]*norm + h[node]*dis^2 (+b)
// (+ReLU). Output either fp32 or split bf16 pair. Edge loop unrolled x4.
// ---------------------------------------------------------------------------
template <int D, bool BIAS, bool RELU, bool SPLIT_OUT>
__global__ __launch_bounds__(256) void k_agg(
    const float* __restrict__ h, const int* __restrict__ row_ptr,
    const int* __restrict__ ssrc, const float* __restrict__ snorm,
    const float* __restrict__ dis, const float* __restrict__ bias,
    float* __restrict__ outf, u16* __restrict__ outh, u16* __restrict__ outl) {
    constexpr int V = D / 64;
    const int wave = threadIdx.x >> 6;
    const int lane = threadIdx.x & 63;
    const int node = blockIdx.x * 4 + wave;
    if (node >= N_NODES) return;

    const int beg = row_ptr[node];
    const int end = row_ptr[node + 1];
    const int base = lane * V;

    float a0[V], a1[V];
    #pragma unroll
    for (int j = 0; j < V; ++j) { a0[j] = 0.f; a1[j] = 0.f; }

#define LOADV(dst, s) do {                                                    \
        const float* p_ = h + (size_t)(s) * D + base;                         \
        if constexpr (V == 4) {                                               \
            float4 t_ = *reinterpret_cast<const float4*>(p_);                 \
            dst[0] = t_.x; dst[1] = t_.y; dst[2] = t_.z; dst[3] = t_.w;       \
        } else {                                                              \
            float2 t_ = *reinterpret_cast<const float2*>(p_);                 \
            dst[0] = t_.x; dst[1] = t_.y;                                     \
        }                                                                     \
    } while (0)

    int e = beg;
    for (; e + 4 <= end; e += 4) {
        const int s0 = ssrc[e], s1 = ssrc[e + 1], s2 = ssrc[e + 2], s3 = ssrc[e + 3];
        const float w0 = snorm[e], w1 = snorm[e + 1], w2 = snorm[e + 2], w3 = snorm[e + 3];
        float v0[V], v1[V], v2[V], v3[V];
        LOADV(v0, s0); LOADV(v1, s1); LOADV(v2, s2); LOADV(v3, s3);
        #pragma unroll
        for (int j = 0; j < V; ++j) {
            a0[j] += v0[j] * w0 + v2[j] * w2;
            a1[j] += v1[j] * w1 + v3[j] * w3;
        }
    }
    for (; e < end; ++e) {
        const int s0 = ssrc[e];
        const float w0 = snorm[e];
        float v0[V];
        LOADV(v0, s0);
        #pragma unroll
        for (int j = 0; j < V; ++j) a0[j] += v0[j] * w0;
    }

    // self loop: norm = dis[node]^2
    {
        float sw = dis[node];
        sw *= sw;
        float vs[V];
        LOADV(vs, node);
        #pragma unroll
        for (int j = 0; j < V; ++j) a1[j] += vs[j] * sw;
    }
#undef LOADV

    float r[V];
    #pragma unroll
    for (int j = 0; j < V; ++j) {
        float v = a0[j] + a1[j];
        if constexpr (BIAS) v += bias[base + j];
        if constexpr (RELU) v = fmaxf(v, 0.f);
        r[j] = v;
    }

    const size_t off = (size_t)node * D + base;
    if constexpr (SPLIT_OUT) {
        u16 hi[V], lo[V];
        #pragma unroll
        for (int j = 0; j < V; ++j) {
            hi[j] = f2bf(r[j]);
            lo[j] = f2bf(r[j] - bf2f(hi[j]));
        }
        if constexpr (V == 4) {
            uint2 ph, pl;
            ph.x = (u32)hi[0] | ((u32)hi[1] << 16);
            ph.y = (u32)hi[2] | ((u32)hi[3] << 16);
            pl.x = (u32)lo[0] | ((u32)lo[1] << 16);
            pl.y = (u32)lo[2] | ((u32)lo[3] << 16);
            *reinterpret_cast<uint2*>(outh + off) = ph;
            *reinterpret_cast<uint2*>(outl + off) = pl;
        } else {
            *reinterpret_cast<u32*>(outh + off) = (u32)hi[0] | ((u32)hi[1] << 16);
            *reinterpret_cast<u32*>(outl + off) = (u32)lo[0] | ((u32)lo[1] << 16);
        }
    } else {
        if constexpr (V == 4) {
            *reinterpret_cast<float4*>(outf + off) = make_float4(r[0], r[1], r[2], r[3]);
        } else {
            *reinterpret_cast<float2*>(outf + off) = make_float2(r[0], r[1]);
        }
    }
}

// ---------------------------------------------------------------------------

extern "C" void kernel_launch(void* const* d_in, const int* in_sizes, int n_in,
                              void* d_out, int out_size, void* d_ws, size_t ws_size,
                              hipStream_t stream) {
    const float* x  = (const float*)d_in[0];
    const int*   ei = (const int*)d_in[1];
    const float* W1 = (const float*)d_in[2];
    const float* b1 = (const float*)d_in[3];
    const float* W2 = (const float*)d_in[4];
    const float* b2 = (const float*)d_in[5];
    const float* W3 = (const float*)d_in[6];
    const float* b3 = (const float*)d_in[7];
    float* out = (float*)d_out;

    const int N = N_NODES;
    const int E = in_sizes[1] / 2;

    char* ws = (char*)d_ws;
    size_t o = 0;
    auto take = [&](size_t bytes) {
        void* p = ws + o;
        o += (bytes + 255) & ~(size_t)255;
        return p;
    };
    float* dis     = (float*)take((size_t)N * 4);
    int*   row_ptr = (int*)  take((size_t)(N + 1) * 4);
    int*   cnt_cur = (int*)  take((size_t)N * 4);
    int*   ssrc    = (int*)  take((size_t)E * 4);
    float* snorm   = (float*)take((size_t)E * 4);
    u16* wt1h = (u16*)take((size_t)256 * 128 * 2);
    u16* wt1l = (u16*)take((size_t)256 * 128 * 2);
    u16* wt2h = (u16*)take((size_t)256 * 256 * 2);
    u16* wt2l = (u16*)take((size_t)256 * 256 * 2);
    u16* wt3h = (u16*)take((size_t)128 * 256 * 2);
    u16* wt3l = (u16*)take((size_t)128 * 256 * 2);
    // slotA: xa pair (51.2MB) -> g2 (102.4MB) -> g3 (51.2MB); lifetimes disjoint
    char* slotA = (char*)take((size_t)N * 256 * 4);
    // slotB: h1 pair -> h2 pair (each 2 * M_PAD*256*2 B); lifetimes disjoint
    char* slotB = (char*)take((size_t)2 * M_PAD * 256 * 2);
    (void)ws_size; (void)n_in; (void)out_size;

    u16*   xah = (u16*)slotA;
    u16*   xal = xah + (size_t)M_PAD * 128;
    float* g2  = (float*)slotA;
    float* g3  = (float*)slotA;
    u16*   h1h = (u16*)slotB;
    u16*   h1l = h1h + (size_t)M_PAD * 256;
    u16*   h2h = (u16*)slotB;
    u16*   h2l = h2h + (size_t)M_PAD * 256;

    const int nb_nodes = (N + 255) / 256;
    const int nb_edges = (E + 255) / 256;

    // ---- graph prep ----
    k_zero_int<<<nb_nodes, 256, 0, stream>>>(cnt_cur, N);
    k_count<<<nb_edges, 256, 0, stream>>>(ei, E, cnt_cur);
    k_dis<<<nb_nodes, 256, 0, stream>>>(cnt_cur, dis, N);
    k_scan<<<1, 1024, 0, stream>>>(cnt_cur, row_ptr, N);
    k_copy_int<<<nb_nodes, 256, 0, stream>>>(row_ptr, cnt_cur, N);
    k_scatter<<<nb_edges, 256, 0, stream>>>(ei, E, dis, cnt_cur, ssrc, snorm);

    // ---- weight transpose+split ----
    k_prep_w<<<256, 256, 0, stream>>>(W1, wt1h, wt1l, 128, 256);
    k_prep_w<<<256, 256, 0, stream>>>(W2, wt2h, wt2l, 256, 256);
    k_prep_w<<<128, 256, 0, stream>>>(W3, wt3h, wt3l, 256, 128);

    const int agg_blocks = (N + 3) / 4;
    const int m_blocks = M_PAD / 128;  // 782

    // ---- layer 1: xa = A*x (D=128, linearity) ; h1 = relu(xa@W1 + b1) ----
    k_agg<128, false, false, true><<<agg_blocks, 256, 0, stream>>>(
        x, row_ptr, ssrc, snorm, dis, nullptr, nullptr, xah, xal);
    k_gemm_split<true, true, true><<<dim3(2, m_blocks), 256, 0, stream>>>(
        xah, xal, wt1h, wt1l, b1, nullptr, h1h, h1l, N, 256, 128);

    // ---- layer 2: g2 = h1@W2 ; h2 = relu(A*g2 + b2) ----
    k_gemm_split<false, false, false><<<dim3(2, m_blocks), 256, 0, stream>>>(
        h1h, h1l, wt2h, wt2l, nullptr, g2, nullptr, nullptr, N, 256, 256);
    k_agg<256, true, true, true><<<agg_blocks, 256, 0, stream>>>(
        g2, row_ptr, ssrc, snorm, dis, b2, nullptr, h2h, h2l);

    // ---- layer 3: g3 = h2@W3 ; out = A*g3 + b3 ----
    k_gemm_split<false, false, false><<<dim3(1, m_blocks), 256, 0, stream>>>(
        h2h, h2l, wt3h, wt3l, nullptr, g3, nullptr, nullptr, N, 128, 256);
    k_agg<128, true, false, false><<<agg_blocks, 256, 0, stream>>>(
        g3, row_ptr, ssrc, snorm, dis, b3, out, nullptr, nullptr);
}

// Round 4
// 813.769 us; speedup vs baseline: 1.5948x; 1.2793x over previous
//
#include <hip/hip_runtime.h>
#include <hip/hip_bf16.h>

#define N_NODES 100000
#define M_PAD   100096   // 782 * 128 — GEMM A-buffers padded so staging never goes OOB

typedef __attribute__((ext_vector_type(8))) short s8v;   // 8 x bf16 (4 VGPR) MFMA operand
typedef __attribute__((ext_vector_type(4))) float f4v;   // MFMA accumulator
typedef unsigned short u16;
typedef unsigned int   u32;

__device__ __forceinline__ u16 f2bf(float v) {
    __hip_bfloat16 b = __float2bfloat16(v);
    return __builtin_bit_cast(u16, b);
}
__device__ __forceinline__ float bf2f(u16 u) {
    u32 t = (u32)u << 16;
    return __builtin_bit_cast(float, t);
}
__device__ __forceinline__ float bflo(u32 p) { return __builtin_bit_cast(float, p << 16); }
__device__ __forceinline__ float bfhi(u32 p) { return __builtin_bit_cast(float, p & 0xffff0000u); }

// async global->LDS, 16B per lane; LDS dest is wave-uniform base + lane*16
__device__ __forceinline__ void gl_lds16(const void* g, void* l) {
    __builtin_amdgcn_global_load_lds(
        (const __attribute__((address_space(1))) void*)g,
        (__attribute__((address_space(3))) void*)l, 16, 0, 0);
}

// ---------------------------------------------------------------------------
// Graph prep
// ---------------------------------------------------------------------------

__global__ __launch_bounds__(256) void k_zero_int(int* __restrict__ p, int n) {
    int i = blockIdx.x * 256 + threadIdx.x;
    if (i < n) p[i] = 0;
}

__global__ __launch_bounds__(256) void k_count(const int* __restrict__ ei, int E,
                                               int* __restrict__ cnt) {
    for (int e = blockIdx.x * 256 + threadIdx.x; e < E; e += gridDim.x * 256)
        atomicAdd(&cnt[ei[E + e]], 1);
}

__global__ __launch_bounds__(256) void k_dis(const int* __restrict__ cnt,
                                             float* __restrict__ dis, int n) {
    int i = blockIdx.x * 256 + threadIdx.x;
    if (i < n) dis[i] = 1.0f / sqrtf((float)(cnt[i] + 1));
}

__global__ __launch_bounds__(1024) void k_scan(const int* __restrict__ cnt,
                                               int* __restrict__ row_ptr, int n) {
    __shared__ int wsum[16];
    const int tid = threadIdx.x;
    const int lane = tid & 63;
    const int wv = tid >> 6;
    int offset = 0;
    for (int base = 0; base < n; base += 1024) {
        int i = base + tid;
        int v = (i < n) ? cnt[i] : 0;
        int x = v;
        #pragma unroll
        for (int d = 1; d < 64; d <<= 1) {
            int t = __shfl_up(x, d, 64);
            if (lane >= d) x += t;
        }
        if (lane == 63) wsum[wv] = x;
        __syncthreads();
        int woff = 0, total = 0;
        #pragma unroll
        for (int w = 0; w < 16; ++w) {
            int s = wsum[w];
            if (w < wv) woff += s;
            total += s;
        }
        if (i < n) row_ptr[i] = offset + woff + x - v;  // exclusive
        offset += total;
        __syncthreads();
    }
    if (tid == 0) row_ptr[n] = offset;
}

__global__ __launch_bounds__(256) void k_copy_int(const int* __restrict__ s,
                                                  int* __restrict__ d, int n) {
    int i = blockIdx.x * 256 + threadIdx.x;
    if (i < n) d[i] = s[i];
}

__global__ __launch_bounds__(256) void k_scatter(const int* __restrict__ ei, int E,
                                                 const float* __restrict__ dis,
                                                 int* __restrict__ cursor,
                                                 int* __restrict__ ssrc,
                                                 float* __restrict__ snorm) {
    for (int e = blockIdx.x * 256 + threadIdx.x; e < E; e += gridDim.x * 256) {
        int s = ei[e];
        int d = ei[E + e];
        int pos = atomicAdd(&cursor[d], 1);
        ssrc[pos] = s;
        snorm[pos] = dis[s] * dis[d];
    }
}

// ---------------------------------------------------------------------------
// Weight prep: W[K][N] fp32 -> transposed split Wt_hi/Wt_lo [N][K] bf16
// ---------------------------------------------------------------------------
__global__ __launch_bounds__(256) void k_prep_w(const float* __restrict__ W,
                                                u16* __restrict__ Wth,
                                                u16* __restrict__ Wtl,
                                                int K, int N) {
    const int n = blockIdx.x;
    for (int k = threadIdx.x; k < K; k += 256) {
        float v = W[(size_t)k * N + n];
        u16 hi = f2bf(v);
        Wth[(size_t)n * K + k] = hi;
        Wtl[(size_t)n * K + k] = f2bf(v - bf2f(hi));
    }
}

// x fp32 -> bf16 (8 elems/thread)
__global__ __launch_bounds__(256) void k_x2bf(const float* __restrict__ x,
                                              u16* __restrict__ xb, long n8) {
    long i = (long)blockIdx.x * 256 + threadIdx.x;
    if (i >= n8) return;
    const float4 a = *reinterpret_cast<const float4*>(x + i * 8);
    const float4 b = *reinterpret_cast<const float4*>(x + i * 8 + 4);
    uint4 p;
    p.x = (u32)f2bf(a.x) | ((u32)f2bf(a.y) << 16);
    p.y = (u32)f2bf(a.z) | ((u32)f2bf(a.w) << 16);
    p.z = (u32)f2bf(b.x) | ((u32)f2bf(b.y) << 16);
    p.w = (u32)f2bf(b.z) | ((u32)f2bf(b.w) << 16);
    *reinterpret_cast<uint4*>(xb + i * 8) = p;
}

// ---------------------------------------------------------------------------
// Split-bf16 MFMA GEMM, 3-product scheme, SWAPPED operands so each lane holds
// 4 consecutive N-columns of one M-row -> vectorized row-major stores.
//   mfma(a=Bt_frag, b=A_frag): D: m = lane&15, n = (lane>>4)*4 + r
// Tile 128x128xBK32; 4 waves of 64x64.
// ---------------------------------------------------------------------------
template <bool BIAS, bool RELU, bool SPLIT_OUT>
__global__ __launch_bounds__(256) void k_gemm_split(
    const u16* __restrict__ Ah, const u16* __restrict__ Al,
    const u16* __restrict__ Bth, const u16* __restrict__ Btl,
    const float* __restrict__ bias,
    u16* __restrict__ Ch, u16* __restrict__ Cl,
    int M, int N, int K) {
    __shared__ u16 Ahs[128 * 32];
    __shared__ u16 Als[128 * 32];
    __shared__ u16 Bhs[128 * 32];
    __shared__ u16 Bls[128 * 32];

    const int tid  = threadIdx.x;
    const int wid  = tid >> 6;
    const int lane = tid & 63;
    const int wm = wid >> 1;
    const int wn = wid & 1;
    const int row0 = blockIdx.y * 128;
    const int n0   = blockIdx.x * 128;

    const int srow  = lane >> 2;        // staging: row within 16-row group
    const int sbyte = (lane & 3) * 16;  // staging: byte offset within 64B row
    const int fr = lane & 15;           // fragment row index within 16
    const int kg = (lane >> 4) * 8;     // fragment k offset (bf16 elements)

    f4v acc[4][4];
    #pragma unroll
    for (int t = 0; t < 4; ++t)
        #pragma unroll
        for (int u = 0; u < 4; ++u)
            acc[t][u] = (f4v){0.f, 0.f, 0.f, 0.f};

    for (int k0 = 0; k0 < K; k0 += 32) {
        #pragma unroll
        for (int g = 0; g < 2; ++g) {
            const int rloc = wid * 32 + g * 16;
            const size_t ga = (size_t)(row0 + rloc + srow) * K + k0;
            gl_lds16((const char*)(Ah + ga) + sbyte, &Ahs[rloc * 32]);
            gl_lds16((const char*)(Al + ga) + sbyte, &Als[rloc * 32]);
            const size_t gb = (size_t)(n0 + rloc + srow) * K + k0;
            gl_lds16((const char*)(Bth + gb) + sbyte, &Bhs[rloc * 32]);
            gl_lds16((const char*)(Btl + gb) + sbyte, &Bls[rloc * 32]);
        }
        __syncthreads();

        // a-operands from Bt (n side), b-operands from A (m side)
        s8v nh[4], nl[4];
        #pragma unroll
        for (int u = 0; u < 4; ++u) {
            const int rb = (wn * 64 + u * 16 + fr) * 32 + kg;
            nh[u] = *(const s8v*)&Bhs[rb];
            nl[u] = *(const s8v*)&Bls[rb];
        }
        #pragma unroll
        for (int t = 0; t < 4; ++t) {
            const int ra = (wm * 64 + t * 16 + fr) * 32 + kg;
            const s8v mh = *(const s8v*)&Ahs[ra];
            const s8v ml = *(const s8v*)&Als[ra];
            #pragma unroll
            for (int u = 0; u < 4; ++u) {
                acc[t][u] = __builtin_amdgcn_mfma_f32_16x16x32_bf16(nh[u], mh, acc[t][u], 0, 0, 0);
                acc[t][u] = __builtin_amdgcn_mfma_f32_16x16x32_bf16(nl[u], mh, acc[t][u], 0, 0, 0);
                acc[t][u] = __builtin_amdgcn_mfma_f32_16x16x32_bf16(nh[u], ml, acc[t][u], 0, 0, 0);
            }
        }
        __syncthreads();
    }

    const int ncol = (lane >> 4) * 4;   // 4 consecutive n-columns per lane
    #pragma unroll
    for (int t = 0; t < 4; ++t) {
        const int grow = row0 + wm * 64 + t * 16 + fr;
        if (grow < M) {
            #pragma unroll
            for (int u = 0; u < 4; ++u) {
                const int nb = n0 + wn * 64 + u * 16 + ncol;
                float v[4];
                #pragma unroll
                for (int r = 0; r < 4; ++r) {
                    float z = acc[t][u][r];
                    if constexpr (BIAS) z += bias[nb + r];
                    if constexpr (RELU) z = fmaxf(z, 0.f);
                    v[r] = z;
                }
                const size_t off = (size_t)grow * N + nb;
                u16 hi[4];
                #pragma unroll
                for (int r = 0; r < 4; ++r) hi[r] = f2bf(v[r]);
                uint2 ph;
                ph.x = (u32)hi[0] | ((u32)hi[1] << 16);
                ph.y = (u32)hi[2] | ((u32)hi[3] << 16);
                *reinterpret_cast<uint2*>(Ch + off) = ph;
                if constexpr (SPLIT_OUT) {
                    uint2 pl;
                    u16 lo[4];
                    #pragma unroll
                    for (int r = 0; r < 4; ++r) lo[r] = f2bf(v[r] - bf2f(hi[r]));
                    pl.x = (u32)lo[0] | ((u32)lo[1] << 16);
                    pl.y = (u32)lo[2] | ((u32)lo[3] << 16);
                    *reinterpret_cast<uint2*>(Cl + off) = pl;
                }
            }
        }
    }
}

// ---------------------------------------------------------------------------
// Aggregation from BF16 features: one wave per node, fp32 accumulate.
// res = sum_in h[src]*norm + h[node]*dis^2 (+bias) (+ReLU).
// OUT_MODE: 0 = fp32, 1 = split bf16 pair.
// ---------------------------------------------------------------------------
template <int D, bool BIAS, bool RELU, int OUT_MODE>
__global__ __launch_bounds__(256) void k_agg(
    const u16* __restrict__ h, const int* __restrict__ row_ptr,
    const int* __restrict__ ssrc, const float* __restrict__ snorm,
    const float* __restrict__ dis, const float* __restrict__ bias,
    float* __restrict__ outf, u16* __restrict__ outh, u16* __restrict__ outl) {
    constexpr int V = D / 64;   // bf16 elems per lane: 4 (D=256) or 2 (D=128)
    const int wave = threadIdx.x >> 6;
    const int lane = threadIdx.x & 63;
    const int node = blockIdx.x * 4 + wave;
    if (node >= N_NODES) return;

    const int beg = row_ptr[node];
    const int end = row_ptr[node + 1];
    const int base = lane * V;

    float a0[V], a1[V];
    #pragma unroll
    for (int j = 0; j < V; ++j) { a0[j] = 0.f; a1[j] = 0.f; }

#define LOADV(dst, s) do {                                                    \
        const u16* p_ = h + (size_t)(s) * D + base;                           \
        if constexpr (V == 4) {                                               \
            uint2 t_ = *reinterpret_cast<const uint2*>(p_);                   \
            dst[0] = bflo(t_.x); dst[1] = bfhi(t_.x);                         \
            dst[2] = bflo(t_.y); dst[3] = bfhi(t_.y);                         \
        } else {                                                              \
            u32 t_ = *reinterpret_cast<const u32*>(p_);                       \
            dst[0] = bflo(t_); dst[1] = bfhi(t_);                             \
        }                                                                     \
    } while (0)

    int e = beg;
    for (; e + 4 <= end; e += 4) {
        const int s0 = ssrc[e], s1 = ssrc[e + 1], s2 = ssrc[e + 2], s3 = ssrc[e + 3];
        const float w0 = snorm[e], w1 = snorm[e + 1], w2 = snorm[e + 2], w3 = snorm[e + 3];
        float v0[V], v1[V], v2[V], v3[V];
        LOADV(v0, s0); LOADV(v1, s1); LOADV(v2, s2); LOADV(v3, s3);
        #pragma unroll
        for (int j = 0; j < V; ++j) {
            a0[j] += v0[j] * w0 + v2[j] * w2;
            a1[j] += v1[j] * w1 + v3[j] * w3;
        }
    }
    for (; e < end; ++e) {
        const int s0 = ssrc[e];
        const float w0 = snorm[e];
        float v0[V];
        LOADV(v0, s0);
        #pragma unroll
        for (int j = 0; j < V; ++j) a0[j] += v0[j] * w0;
    }

    // self loop: norm = dis[node]^2
    {
        float sw = dis[node];
        sw *= sw;
        float vs[V];
        LOADV(vs, node);
        #pragma unroll
        for (int j = 0; j < V; ++j) a1[j] += vs[j] * sw;
    }
#undef LOADV

    float r[V];
    #pragma unroll
    for (int j = 0; j < V; ++j) {
        float v = a0[j] + a1[j];
        if constexpr (BIAS) v += bias[base + j];
        if constexpr (RELU) v = fmaxf(v, 0.f);
        r[j] = v;
    }

    const size_t off = (size_t)node * D + base;
    if constexpr (OUT_MODE == 1) {
        u16 hi[V], lo[V];
        #pragma unroll
        for (int j = 0; j < V; ++j) {
            hi[j] = f2bf(r[j]);
            lo[j] = f2bf(r[j] - bf2f(hi[j]));
        }
        if constexpr (V == 4) {
            uint2 ph, pl;
            ph.x = (u32)hi[0] | ((u32)hi[1] << 16);
            ph.y = (u32)hi[2] | ((u32)hi[3] << 16);
            pl.x = (u32)lo[0] | ((u32)lo[1] << 16);
            pl.y = (u32)lo[2] | ((u32)lo[3] << 16);
            *reinterpret_cast<uint2*>(outh + off) = ph;
            *reinterpret_cast<uint2*>(outl + off) = pl;
        } else {
            *reinterpret_cast<u32*>(outh + off) = (u32)hi[0] | ((u32)hi[1] << 16);
            *reinterpret_cast<u32*>(outl + off) = (u32)lo[0] | ((u32)lo[1] << 16);
        }
    } else {
        if constexpr (V == 4) {
            *reinterpret_cast<float4*>(outf + off) = make_float4(r[0], r[1], r[2], r[3]);
        } else {
            *reinterpret_cast<float2*>(outf + off) = make_float2(r[0], r[1]);
        }
    }
}

// ---------------------------------------------------------------------------

extern "C" void kernel_launch(void* const* d_in, const int* in_sizes, int n_in,
                              void* d_out, int out_size, void* d_ws, size_t ws_size,
                              hipStream_t stream) {
    const float* x  = (const float*)d_in[0];
    const int*   ei = (const int*)d_in[1];
    const float* W1 = (const float*)d_in[2];
    const float* b1 = (const float*)d_in[3];
    const float* W2 = (const float*)d_in[4];
    const float* b2 = (const float*)d_in[5];
    const float* W3 = (const float*)d_in[6];
    const float* b3 = (const float*)d_in[7];
    float* out = (float*)d_out;

    const int N = N_NODES;
    const int E = in_sizes[1] / 2;

    char* ws = (char*)d_ws;
    size_t o = 0;
    auto take = [&](size_t bytes) {
        void* p = ws + o;
        o += (bytes + 255) & ~(size_t)255;
        return p;
    };
    float* dis     = (float*)take((size_t)N * 4);
    int*   row_ptr = (int*)  take((size_t)(N + 1) * 4);
    int*   cnt_cur = (int*)  take((size_t)N * 4);
    int*   ssrc    = (int*)  take((size_t)E * 4);
    float* snorm   = (float*)take((size_t)E * 4);
    u16* wt1h = (u16*)take((size_t)256 * 128 * 2);
    u16* wt1l = (u16*)take((size_t)256 * 128 * 2);
    u16* wt2h = (u16*)take((size_t)256 * 256 * 2);
    u16* wt2l = (u16*)take((size_t)256 * 256 * 2);
    u16* wt3h = (u16*)take((size_t)128 * 256 * 2);
    u16* wt3l = (u16*)take((size_t)128 * 256 * 2);
    // liveness chain 2-coloring:
    //   slot1: xb (25.6MB) -> h1 pair (102.5MB) -> (h1 dead after GEMM2)
    //   slot2: xa pair (51.2MB) -> g2 (51.2MB) -> g3 (25.6MB)
    //   slot1 again: h2 pair (102.5MB) after h1 dead
    char* slot1 = (char*)take((size_t)2 * M_PAD * 256 * 2);   // 102.5 MB
    char* slot2 = (char*)take((size_t)2 * M_PAD * 128 * 2);   // 51.2 MB
    (void)ws_size; (void)n_in; (void)out_size;

    u16* xb  = (u16*)slot1;
    u16* h1h = (u16*)slot1;
    u16* h1l = h1h + (size_t)M_PAD * 256;
    u16* h2h = (u16*)slot1;                 // after h1 dead (GEMM2 done)
    u16* h2l = h2h + (size_t)M_PAD * 256;
    u16* xah = (u16*)slot2;
    u16* xal = xah + (size_t)M_PAD * 128;
    u16* g2  = (u16*)slot2;                 // after xa dead (GEMM1 done)
    u16* g3  = (u16*)slot2;                 // after g2 dead (agg2 done)

    const int nb_nodes = (N + 255) / 256;
    const int nb_edges = (E + 255) / 256;

    // ---- graph prep ----
    k_zero_int<<<nb_nodes, 256, 0, stream>>>(cnt_cur, N);
    k_count<<<nb_edges, 256, 0, stream>>>(ei, E, cnt_cur);
    k_dis<<<nb_nodes, 256, 0, stream>>>(cnt_cur, dis, N);
    k_scan<<<1, 1024, 0, stream>>>(cnt_cur, row_ptr, N);
    k_copy_int<<<nb_nodes, 256, 0, stream>>>(row_ptr, cnt_cur, N);
    k_scatter<<<nb_edges, 256, 0, stream>>>(ei, E, dis, cnt_cur, ssrc, snorm);

    // ---- weight transpose+split, x -> bf16 ----
    k_prep_w<<<256, 256, 0, stream>>>(W1, wt1h, wt1l, 128, 256);
    k_prep_w<<<256, 256, 0, stream>>>(W2, wt2h, wt2l, 256, 256);
    k_prep_w<<<128, 256, 0, stream>>>(W3, wt3h, wt3l, 256, 128);
    const long n8 = (long)N * 128 / 8;
    k_x2bf<<<(int)((n8 + 255) / 256), 256, 0, stream>>>(x, xb, n8);

    const int agg_blocks = (N + 3) / 4;
    const int m_blocks = M_PAD / 128;  // 782

    // ---- layer 1: xa = A*xb (D=128) ; h1 = relu(xa@W1 + b1) [split out] ----
    k_agg<128, false, false, 1><<<agg_blocks, 256, 0, stream>>>(
        xb, row_ptr, ssrc, snorm, dis, nullptr, nullptr, xah, xal);
    k_gemm_split<true, true, true><<<dim3(2, m_blocks), 256, 0, stream>>>(
        xah, xal, wt1h, wt1l, b1, h1h, h1l, N, 256, 128);

    // ---- layer 2: g2 = h1@W2 [bf16 out] ; h2 = relu(A*g2 + b2) [split out] ----
    k_gemm_split<false, false, false><<<dim3(2, m_blocks), 256, 0, stream>>>(
        h1h, h1l, wt2h, wt2l, nullptr, g2, nullptr, N, 256, 256);
    k_agg<256, true, true, 1><<<agg_blocks, 256, 0, stream>>>(
        g2, row_ptr, ssrc, snorm, dis, b2, nullptr, h2h, h2l);

    // ---- layer 3: g3 = h2@W3 [bf16 out] ; out = A*g3 + b3 [fp32 out] ----
    k_gemm_split<false, false, false><<<dim3(1, m_blocks), 256, 0, stream>>>(
        h2h, h2l, wt3h, wt3l, nullptr, g3, nullptr, N, 128, 256);
    k_agg<128, true, false, 0><<<agg_blocks, 256, 0, stream>>>(
        g3, row_ptr, ssrc, snorm, dis, b3, out, nullptr, nullptr);
}

// Round 6
// 692.866 us; speedup vs baseline: 1.8731x; 1.1745x over previous
//
#include <hip/hip_runtime.h>
#include <hip/hip_bf16.h>

#define N_NODES 100000
#define M_PAD   100096   // 782 * 128 — GEMM A-buffers padded so staging never goes OOB
#define SCAN_B  98       // ceil(N_NODES / 1024)

typedef __attribute__((ext_vector_type(8))) short s8v;   // 8 x bf16 (4 VGPR) MFMA operand
typedef __attribute__((ext_vector_type(4))) float f4v;   // MFMA accumulator
typedef unsigned short u16;
typedef unsigned int   u32;

__device__ __forceinline__ u16 f2bf(float v) {
    __hip_bfloat16 b = __float2bfloat16(v);
    return __builtin_bit_cast(u16, b);
}
__device__ __forceinline__ float bf2f(u16 u) {
    u32 t = (u32)u << 16;
    return __builtin_bit_cast(float, t);
}
__device__ __forceinline__ float bflo(u32 p) { return __builtin_bit_cast(float, p << 16); }
__device__ __forceinline__ float bfhi(u32 p) { return __builtin_bit_cast(float, p & 0xffff0000u); }

// async global->LDS, 16B per lane; LDS dest is wave-uniform base + lane*16
__device__ __forceinline__ void gl_lds16(const void* g, void* l) {
    __builtin_amdgcn_global_load_lds(
        (const __attribute__((address_space(1))) void*)g,
        (__attribute__((address_space(3))) void*)l, 16, 0, 0);
}

// ---------------------------------------------------------------------------
// Graph prep
// ---------------------------------------------------------------------------

__global__ __launch_bounds__(256) void k_zero_int(int* __restrict__ p, int n) {
    int i = blockIdx.x * 256 + threadIdx.x;
    if (i < n) p[i] = 0;
}

__global__ __launch_bounds__(256) void k_count(const int* __restrict__ ei, int E,
                                               int* __restrict__ cnt) {
    for (int e = blockIdx.x * 256 + threadIdx.x; e < E; e += gridDim.x * 256)
        atomicAdd(&cnt[ei[E + e]], 1);
}

// scan phase A: per-block exclusive scan (1024 elems/block) + block sums + dis
__global__ __launch_bounds__(1024) void k_scan_a(const int* __restrict__ cnt,
                                                 int* __restrict__ row_ptr,
                                                 int* __restrict__ bsum,
                                                 float* __restrict__ dis, int n) {
    __shared__ int wsum[16];
    const int tid = threadIdx.x;
    const int lane = tid & 63;
    const int wv = tid >> 6;
    const int i = blockIdx.x * 1024 + tid;
    const int v = (i < n) ? cnt[i] : 0;
    if (i < n) dis[i] = 1.0f / sqrtf((float)(v + 1));
    int x = v;
    #pragma unroll
    for (int d = 1; d < 64; d <<= 1) {
        int t = __shfl_up(x, d, 64);
        if (lane >= d) x += t;
    }
    if (lane == 63) wsum[wv] = x;
    __syncthreads();
    int woff = 0, total = 0;
    #pragma unroll
    for (int w = 0; w < 16; ++w) {
        int s = wsum[w];
        if (w < wv) woff += s;
        total += s;
    }
    if (i < n) row_ptr[i] = woff + x - v;  // block-local exclusive
    if (tid == 0) bsum[blockIdx.x] = total;
}

// scan phase B: exclusive scan of SCAN_B block sums (1 block, 128 thr)
__global__ __launch_bounds__(128) void k_scan_b(int* __restrict__ bsum,
                                                int* __restrict__ row_ptr,
                                                int nparts, int n, int total_edges) {
    __shared__ int w0tot;
    const int tid = threadIdx.x;
    const int lane = tid & 63;
    const int v = (tid < nparts) ? bsum[tid] : 0;
    int x = v;
    #pragma unroll
    for (int d = 1; d < 64; d <<= 1) {
        int t = __shfl_up(x, d, 64);
        if (lane >= d) x += t;
    }
    if (tid == 63) w0tot = x;
    __syncthreads();
    int excl = x - v + ((tid >= 64) ? w0tot : 0);
    if (tid < nparts) bsum[tid] = excl;
    if (tid == 0) row_ptr[n] = total_edges;
}

// scan phase C: add block offset, init cursor
__global__ __launch_bounds__(1024) void k_scan_c(int* __restrict__ row_ptr,
                                                 const int* __restrict__ bsum,
                                                 int* __restrict__ cursor, int n) {
    const int i = blockIdx.x * 1024 + threadIdx.x;
    if (i < n) {
        const int r = row_ptr[i] + bsum[blockIdx.x];
        row_ptr[i] = r;
        cursor[i] = r;
    }
}

// counting-sort scatter: edge -> slot in dst's CSR row; pack (src, norm) as int2
__global__ __launch_bounds__(256) void k_scatter(const int* __restrict__ ei, int E,
                                                 const float* __restrict__ dis,
                                                 int* __restrict__ cursor,
                                                 int2* __restrict__ edat) {
    for (int e = blockIdx.x * 256 + threadIdx.x; e < E; e += gridDim.x * 256) {
        const int s = ei[e];
        const int d = ei[E + e];
        const int pos = atomicAdd(&cursor[d], 1);
        edat[pos] = make_int2(s, __float_as_int(dis[s] * dis[d]));
    }
}

// ---------------------------------------------------------------------------
// Weight prep: W[K][N] fp32 -> transposed split Wt_hi/Wt_lo [N][K] bf16
// ---------------------------------------------------------------------------
__global__ __launch_bounds__(256) void k_prep_w(const float* __restrict__ W,
                                                u16* __restrict__ Wth,
                                                u16* __restrict__ Wtl,
                                                int K, int N) {
    const int n = blockIdx.x;
    for (int k = threadIdx.x; k < K; k += 256) {
        float v = W[(size_t)k * N + n];
        u16 hi = f2bf(v);
        Wth[(size_t)n * K + k] = hi;
        Wtl[(size_t)n * K + k] = f2bf(v - bf2f(hi));
    }
}

// x fp32 -> bf16 (8 elems/thread)
__global__ __launch_bounds__(256) void k_x2bf(const float* __restrict__ x,
                                              u16* __restrict__ xb, long n8) {
    long i = (long)blockIdx.x * 256 + threadIdx.x;
    if (i >= n8) return;
    const float4 a = *reinterpret_cast<const float4*>(x + i * 8);
    const float4 b = *reinterpret_cast<const float4*>(x + i * 8 + 4);
    uint4 p;
    p.x = (u32)f2bf(a.x) | ((u32)f2bf(a.y) << 16);
    p.y = (u32)f2bf(a.z) | ((u32)f2bf(a.w) << 16);
    p.z = (u32)f2bf(b.x) | ((u32)f2bf(b.y) << 16);
    p.w = (u32)f2bf(b.z) | ((u32)f2bf(b.w) << 16);
    *reinterpret_cast<uint4*>(xb + i * 8) = p;
}

// ---------------------------------------------------------------------------
// Split-bf16 MFMA GEMM, 3-product scheme, SWAPPED operands so each lane holds
// 4 consecutive N-columns of one M-row -> vectorized row-major stores.
// Tile 128x128xBK32; 4 waves of 64x64.
// ---------------------------------------------------------------------------
template <bool BIAS, bool RELU, bool SPLIT_OUT>
__global__ __launch_bounds__(256) void k_gemm_split(
    const u16* __restrict__ Ah, const u16* __restrict__ Al,
    const u16* __restrict__ Bth, const u16* __restrict__ Btl,
    const float* __restrict__ bias,
    u16* __restrict__ Ch, u16* __restrict__ Cl,
    int M, int N, int K) {
    __shared__ u16 Ahs[128 * 32];
    __shared__ u16 Als[128 * 32];
    __shared__ u16 Bhs[128 * 32];
    __shared__ u16 Bls[128 * 32];

    const int tid  = threadIdx.x;
    const int wid  = tid >> 6;
    const int lane = tid & 63;
    const int wm = wid >> 1;
    const int wn = wid & 1;
    const int row0 = blockIdx.y * 128;
    const int n0   = blockIdx.x * 128;

    const int srow  = lane >> 2;        // staging: row within 16-row group
    const int sbyte = (lane & 3) * 16;  // staging: byte offset within 64B row
    const int fr = lane & 15;           // fragment row index within 16
    const int kg = (lane >> 4) * 8;     // fragment k offset (bf16 elements)

    f4v acc[4][4];
    #pragma unroll
    for (int t = 0; t < 4; ++t)
        #pragma unroll
        for (int u = 0; u < 4; ++u)
            acc[t][u] = (f4v){0.f, 0.f, 0.f, 0.f};

    for (int k0 = 0; k0 < K; k0 += 32) {
        #pragma unroll
        for (int g = 0; g < 2; ++g) {
            const int rloc = wid * 32 + g * 16;
            const size_t ga = (size_t)(row0 + rloc + srow) * K + k0;
            gl_lds16((const char*)(Ah + ga) + sbyte, &Ahs[rloc * 32]);
            gl_lds16((const char*)(Al + ga) + sbyte, &Als[rloc * 32]);
            const size_t gb = (size_t)(n0 + rloc + srow) * K + k0;
            gl_lds16((const char*)(Bth + gb) + sbyte, &Bhs[rloc * 32]);
            gl_lds16((const char*)(Btl + gb) + sbyte, &Bls[rloc * 32]);
        }
        __syncthreads();

        // a-operands from Bt (n side), b-operands from A (m side)
        s8v nh[4], nl[4];
        #pragma unroll
        for (int u = 0; u < 4; ++u) {
            const int rb = (wn * 64 + u * 16 + fr) * 32 + kg;
            nh[u] = *(const s8v*)&Bhs[rb];
            nl[u] = *(const s8v*)&Bls[rb];
        }
        #pragma unroll
        for (int t = 0; t < 4; ++t) {
            const int ra = (wm * 64 + t * 16 + fr) * 32 + kg;
            const s8v mh = *(const s8v*)&Ahs[ra];
            const s8v ml = *(const s8v*)&Als[ra];
            #pragma unroll
            for (int u = 0; u < 4; ++u) {
                acc[t][u] = __builtin_amdgcn_mfma_f32_16x16x32_bf16(nh[u], mh, acc[t][u], 0, 0, 0);
                acc[t][u] = __builtin_amdgcn_mfma_f32_16x16x32_bf16(nl[u], mh, acc[t][u], 0, 0, 0);
                acc[t][u] = __builtin_amdgcn_mfma_f32_16x16x32_bf16(nh[u], ml, acc[t][u], 0, 0, 0);
            }
        }
        __syncthreads();
    }

    const int ncol = (lane >> 4) * 4;   // 4 consecutive n-columns per lane
    #pragma unroll
    for (int t = 0; t < 4; ++t) {
        const int grow = row0 + wm * 64 + t * 16 + fr;
        if (grow < M) {
            #pragma unroll
            for (int u = 0; u < 4; ++u) {
                const int nb = n0 + wn * 64 + u * 16 + ncol;
                float v[4];
                #pragma unroll
                for (int r = 0; r < 4; ++r) {
                    float z = acc[t][u][r];
                    if constexpr (BIAS) z += bias[nb + r];
                    if constexpr (RELU) z = fmaxf(z, 0.f);
                    v[r] = z;
                }
                const size_t off = (size_t)grow * N + nb;
                u16 hi[4];
                #pragma unroll
                for (int r = 0; r < 4; ++r) hi[r] = f2bf(v[r]);
                uint2 ph;
                ph.x = (u32)hi[0] | ((u32)hi[1] << 16);
                ph.y = (u32)hi[2] | ((u32)hi[3] << 16);
                *reinterpret_cast<uint2*>(Ch + off) = ph;
                if constexpr (SPLIT_OUT) {
                    uint2 pl;
                    u16 lo[4];
                    #pragma unroll
                    for (int r = 0; r < 4; ++r) lo[r] = f2bf(v[r] - bf2f(hi[r]));
                    pl.x = (u32)lo[0] | ((u32)lo[1] << 16);
                    pl.y = (u32)lo[2] | ((u32)lo[3] << 16);
                    *reinterpret_cast<uint2*>(Cl + off) = pl;
                }
            }
        }
    }
}

// ---------------------------------------------------------------------------
// Aggregation from BF16 features: one wave per node, fp32 accumulate.
// Edge loop unrolled x8 with 4 independent accumulator sets.
// OUT_MODE: 0 = fp32, 1 = split bf16 pair.
// ---------------------------------------------------------------------------
template <int D, bool BIAS, bool RELU, int OUT_MODE>
__global__ __launch_bounds__(256) void k_agg(
    const u16* __restrict__ h, const int* __restrict__ row_ptr,
    const int2* __restrict__ edat,
    const float* __restrict__ dis, const float* __restrict__ bias,
    float* __restrict__ outf, u16* __restrict__ outh, u16* __restrict__ outl) {
    constexpr int V = D / 64;   // bf16 elems per lane: 4 (D=256) or 2 (D=128)
    const int wave = threadIdx.x >> 6;
    const int lane = threadIdx.x & 63;
    const int node = blockIdx.x * 4 + wave;
    if (node >= N_NODES) return;

    const int beg = row_ptr[node];
    const int end = row_ptr[node + 1];
    const int base = lane * V;

    float a[4][V];
    #pragma unroll
    for (int c = 0; c < 4; ++c)
        #pragma unroll
        for (int j = 0; j < V; ++j) a[c][j] = 0.f;

#define LOADV(dst, s) do {                                                    \
        const u16* p_ = h + (size_t)(s) * D + base;                           \
        if constexpr (V == 4) {                                               \
            uint2 t_ = *reinterpret_cast<const uint2*>(p_);                   \
            dst[0] = bflo(t_.x); dst[1] = bfhi(t_.x);                         \
            dst[2] = bflo(t_.y); dst[3] = bfhi(t_.y);                         \
        } else {                                                              \
            u32 t_ = *reinterpret_cast<const u32*>(p_);                       \
            dst[0] = bflo(t_); dst[1] = bfhi(t_);                             \
        }                                                                     \
    } while (0)

    int e = beg;
    for (; e + 8 <= end; e += 8) {
        int2 ed[8];
        float v[8][V];
        #pragma unroll
        for (int j = 0; j < 8; ++j) ed[j] = edat[e + j];
        #pragma unroll
        for (int j = 0; j < 8; ++j) LOADV(v[j], ed[j].x);
        #pragma unroll
        for (int j = 0; j < 8; ++j) {
            const float w = __int_as_float(ed[j].y);
            #pragma unroll
            for (int k = 0; k < V; ++k) a[j & 3][k] += v[j][k] * w;
        }
    }
    for (; e + 2 <= end; e += 2) {
        const int2 e0 = edat[e], e1 = edat[e + 1];
        float v0[V], v1[V];
        LOADV(v0, e0.x); LOADV(v1, e1.x);
        const float w0 = __int_as_float(e0.y), w1 = __int_as_float(e1.y);
        #pragma unroll
        for (int k = 0; k < V; ++k) { a[0][k] += v0[k] * w0; a[1][k] += v1[k] * w1; }
    }
    if (e < end) {
        const int2 e0 = edat[e];
        float v0[V];
        LOADV(v0, e0.x);
        const float w0 = __int_as_float(e0.y);
        #pragma unroll
        for (int k = 0; k < V; ++k) a[2][k] += v0[k] * w0;
    }

    // self loop: norm = dis[node]^2
    {
        float sw = dis[node];
        sw *= sw;
        float vs[V];
        LOADV(vs, node);
        #pragma unroll
        for (int k = 0; k < V; ++k) a[3][k] += vs[k] * sw;
    }
#undef LOADV

    float r[V];
    #pragma unroll
    for (int j = 0; j < V; ++j) {
        float v = (a[0][j] + a[1][j]) + (a[2][j] + a[3][j]);
        if constexpr (BIAS) v += bias[base + j];
        if constexpr (RELU) v = fmaxf(v, 0.f);
        r[j] = v;
    }

    const size_t off = (size_t)node * D + base;
    if constexpr (OUT_MODE == 1) {
        u16 hi[V], lo[V];
        #pragma unroll
        for (int j = 0; j < V; ++j) {
            hi[j] = f2bf(r[j]);
            lo[j] = f2bf(r[j] - bf2f(hi[j]));
        }
        if constexpr (V == 4) {
            uint2 ph, pl;
            ph.x = (u32)hi[0] | ((u32)hi[1] << 16);
            ph.y = (u32)hi[2] | ((u32)hi[3] << 16);
            pl.x = (u32)lo[0] | ((u32)lo[1] << 16);
            pl.y = (u32)lo[2] | ((u32)lo[3] << 16);
            *reinterpret_cast<uint2*>(outh + off) = ph;
            *reinterpret_cast<uint2*>(outl + off) = pl;
        } else {
            *reinterpret_cast<u32*>(outh + off) = (u32)hi[0] | ((u32)hi[1] << 16);
            *reinterpret_cast<u32*>(outl + off) = (u32)lo[0] | ((u32)lo[1] << 16);
        }
    } else {
        if constexpr (V == 4) {
            *reinterpret_cast<float4*>(outf + off) = make_float4(r[0], r[1], r[2], r[3]);
        } else {
            *reinterpret_cast<float2*>(outf + off) = make_float2(r[0], r[1]);
        }
    }
}

// ---------------------------------------------------------------------------

extern "C" void kernel_launch(void* const* d_in, const int* in_sizes, int n_in,
                              void* d_out, int out_size, void* d_ws, size_t ws_size,
                              hipStream_t stream) {
    const float* x  = (const float*)d_in[0];
    const int*   ei = (const int*)d_in[1];
    const float* W1 = (const float*)d_in[2];
    const float* b1 = (const float*)d_in[3];
    const float* W2 = (const float*)d_in[4];
    const float* b2 = (const float*)d_in[5];
    const float* W3 = (const float*)d_in[6];
    const float* b3 = (const float*)d_in[7];
    float* out = (float*)d_out;

    const int N = N_NODES;
    const int E = in_sizes[1] / 2;

    char* ws = (char*)d_ws;
    size_t o = 0;
    auto take = [&](size_t bytes) {
        void* p = ws + o;
        o += (bytes + 255) & ~(size_t)255;
        return p;
    };
    float* dis     = (float*)take((size_t)N * 4);
    int*   row_ptr = (int*)  take((size_t)(N + 1) * 4);
    int*   cnt_cur = (int*)  take((size_t)N * 4);
    int*   bsum    = (int*)  take((size_t)SCAN_B * 4);
    int2*  edat    = (int2*) take((size_t)E * 8);
    u16* wt1h = (u16*)take((size_t)256 * 128 * 2);
    u16* wt1l = (u16*)take((size_t)256 * 128 * 2);
    u16* wt2h = (u16*)take((size_t)256 * 256 * 2);
    u16* wt2l = (u16*)take((size_t)256 * 256 * 2);
    u16* wt3h = (u16*)take((size_t)128 * 256 * 2);
    u16* wt3l = (u16*)take((size_t)128 * 256 * 2);
    // liveness chain 2-coloring:
    //   slot1: xb -> h1 pair -> h2 pair   slot2: xa pair -> g2 -> g3
    char* slot1 = (char*)take((size_t)2 * M_PAD * 256 * 2);   // 102.5 MB
    char* slot2 = (char*)take((size_t)2 * M_PAD * 128 * 2);   // 51.2 MB
    (void)ws_size; (void)n_in; (void)out_size;

    u16* xb  = (u16*)slot1;
    u16* h1h = (u16*)slot1;
    u16* h1l = h1h + (size_t)M_PAD * 256;
    u16* h2h = (u16*)slot1;                 // after h1 dead (GEMM2 done)
    u16* h2l = h2h + (size_t)M_PAD * 256;
    u16* xah = (u16*)slot2;
    u16* xal = xah + (size_t)M_PAD * 128;
    u16* g2  = (u16*)slot2;                 // after xa dead (GEMM1 done)
    u16* g3  = (u16*)slot2;                 // after g2 dead (agg2 done)

    const int nb_nodes = (N + 255) / 256;
    const int nb_edges = (E + 255) / 256;

    // ---- graph prep (parallel scan) ----
    k_zero_int<<<nb_nodes, 256, 0, stream>>>(cnt_cur, N);
    k_count<<<nb_edges, 256, 0, stream>>>(ei, E, cnt_cur);
    k_scan_a<<<SCAN_B, 1024, 0, stream>>>(cnt_cur, row_ptr, bsum, dis, N);
    k_scan_b<<<1, 128, 0, stream>>>(bsum, row_ptr, SCAN_B, N, E);
    k_scan_c<<<SCAN_B, 1024, 0, stream>>>(row_ptr, bsum, cnt_cur, N);
    k_scatter<<<nb_edges, 256, 0, stream>>>(ei, E, dis, cnt_cur, edat);

    // ---- weight transpose+split, x -> bf16 ----
    k_prep_w<<<256, 256, 0, stream>>>(W1, wt1h, wt1l, 128, 256);
    k_prep_w<<<256, 256, 0, stream>>>(W2, wt2h, wt2l, 256, 256);
    k_prep_w<<<128, 256, 0, stream>>>(W3, wt3h, wt3l, 256, 128);
    const long n8 = (long)N * 128 / 8;
    k_x2bf<<<(int)((n8 + 255) / 256), 256, 0, stream>>>(x, xb, n8);

    const int agg_blocks = (N + 3) / 4;
    const int m_blocks = M_PAD / 128;  // 782

    // ---- layer 1: xa = A*xb (D=128) ; h1 = relu(xa@W1 + b1) [split out] ----
    k_agg<128, false, false, 1><<<agg_blocks, 256, 0, stream>>>(
        xb, row_ptr, edat, dis, nullptr, nullptr, xah, xal);
    k_gemm_split<true, true, true><<<dim3(2, m_blocks), 256, 0, stream>>>(
        xah, xal, wt1h, wt1l, b1, h1h, h1l, N, 256, 128);

    // ---- layer 2: g2 = h1@W2 [bf16 out] ; h2 = relu(A*g2 + b2) [split out] ----
    k_gemm_split<false, false, false><<<dim3(2, m_blocks), 256, 0, stream>>>(
        h1h, h1l, wt2h, wt2l, nullptr, g2, nullptr, N, 256, 256);
    k_agg<256, true, true, 1><<<agg_blocks, 256, 0, stream>>>(
        g2, row_ptr, edat, dis, b2, nullptr, h2h, h2l);

    // ---- layer 3: g3 = h2@W3 [bf16 out] ; out = A*g3 + b3 [fp32 out] ----
    k_gemm_split<false, false, false><<<dim3(1, m_blocks), 256, 0, stream>>>(
        h2h, h2l, wt3h, wt3l, nullptr, g3, nullptr, N, 128, 256);
    k_agg<128, true, false, 0><<<agg_blocks, 256, 0, stream>>>(
        g3, row_ptr, edat, dis, b3, out, nullptr, nullptr);
}